// Round 8
// baseline (1606.637 us; speedup 1.0000x reference)
//
#include <hip/hip_runtime.h>
#include <hip/hip_cooperative_groups.h>

namespace cg = cooperative_groups;

#define NN1 32768
#define NE  262144
#define FDIM 256
#define NHEADS 4
#define IN_DIM 128
#define NB 32
#define KK1 512
#define NN2 16384   // NB*KK1
#define KK2 256
#define NN3 8192    // NB*KK2
#define OUT_DIM 256
#define BN_EPS 1e-5f
#define NEG_SLOPE 0.2f

typedef _Float16 half8 __attribute__((ext_vector_type(8)));
typedef _Float16 half4v __attribute__((ext_vector_type(4)));
typedef float floatx4 __attribute__((ext_vector_type(4)));

__device__ __forceinline__ float lrelu(float x) { return x >= 0.f ? x : NEG_SLOPE * x; }
__device__ __forceinline__ float gelu(float v) {
  return 0.5f * v * (1.0f + erff(v * 0.7071067811865476f));
}

// ---------- init: x->fp16, W1^T, W2^T, zero deg1/deg2/inv1/bnstats ----------
__global__ void init_k(const float4* __restrict__ x, half4v* __restrict__ ah,
                       const float* __restrict__ W1, _Float16* __restrict__ bt1,
                       const float* __restrict__ W2, _Float16* __restrict__ bt2,
                       int* __restrict__ deg1, int* __restrict__ deg2,
                       int* __restrict__ inv1, float* __restrict__ bnst) {
  int blk = blockIdx.x, tid = threadIdx.x;
  if (blk < 4096) {                       // x fp32 -> fp16
    int i = blk * 256 + tid;
    float4 v = x[i];
    half4v h;
    h[0] = (_Float16)v.x; h[1] = (_Float16)v.y; h[2] = (_Float16)v.z; h[3] = (_Float16)v.w;
    ah[i] = h;
  } else if (blk < 4224) {                // W1[128][256] -> bt1[256][128]
    int idx = (blk - 4096) * 256 + tid;
    int n = idx >> 7, k = idx & 127;
    bt1[idx] = (_Float16)W1[k * FDIM + n];
  } else if (blk < 4480) {                // W2[256][256] -> bt2[256][256]
    int idx = (blk - 4224) * 256 + tid;
    int n = idx >> 8, k = idx & 255;
    bt2[idx] = (_Float16)W2[k * FDIM + n];
  } else {                                // zero accumulators
    int i = (blk - 4480) * 256 + tid;
    deg1[i] = 0;
    inv1[i] = -1;
    if (i < NN2) deg2[i] = 0;
    if (i < 1024) bnst[i] = 0.f;
  }
}

// ---------------- MFMA fp16 GEMM + fused attn-coef epilogue (+ optional deg ride-along)
// block tile 64(M) x 128(N), BK=32, 4 waves 2x2, wave tile 32x64 (= one head in N)
template <int K, int MBLK, bool RIDE>
__global__ void gemm_attn_k(const _Float16* __restrict__ A, const _Float16* __restrict__ BT,
                            _Float16* __restrict__ C, const float* __restrict__ a_s,
                            const float* __restrict__ a_d, float* __restrict__ asn,
                            float* __restrict__ adn, const int* __restrict__ dstE,
                            int* __restrict__ deg) {
  if (RIDE && (int)blockIdx.y >= MBLK) {  // block-uniform branch: deg count ride-along
    int unit = blockIdx.x + 2 * (blockIdx.y - MBLK);
    int e = unit * 256 + threadIdx.x;
    if (e < NE) {
      int dd = dstE[e];
      if (dd >= 0) atomicAdd(&deg[dd], 1);
    }
    return;
  }
  __shared__ _Float16 As[64 * 40];
  __shared__ _Float16 Bs[128 * 40];
  int tid = threadIdx.x;
  int lane = tid & 63, w = tid >> 6;
  int bm = blockIdx.y * 64, bn = blockIdx.x * 128;
  int wm = (w & 1) * 32, wn = (w >> 1) * 64;
  floatx4 acc[2][4] = {};
  int ar = tid >> 2, ac = (tid & 3) * 8;
  int br = tid >> 1, bc = (tid & 1) * 16;
  int fm = lane & 15, fq = (lane >> 4) * 8;
  for (int k0 = 0; k0 < K; k0 += 32) {
    __syncthreads();
    *(half8*)&As[ar * 40 + ac] = *(const half8*)&A[(size_t)(bm + ar) * K + k0 + ac];
    *(half8*)&Bs[br * 40 + bc] = *(const half8*)&BT[(size_t)(bn + br) * K + k0 + bc];
    *(half8*)&Bs[br * 40 + bc + 8] = *(const half8*)&BT[(size_t)(bn + br) * K + k0 + bc + 8];
    __syncthreads();
    half8 af[2], bf[4];
#pragma unroll
    for (int mt = 0; mt < 2; ++mt)
      af[mt] = *(const half8*)&As[(wm + mt * 16 + fm) * 40 + fq];
#pragma unroll
    for (int nt = 0; nt < 4; ++nt)
      bf[nt] = *(const half8*)&Bs[(wn + nt * 16 + fm) * 40 + fq];
#pragma unroll
    for (int mt = 0; mt < 2; ++mt)
#pragma unroll
      for (int nt = 0; nt < 4; ++nt)
        acc[mt][nt] = __builtin_amdgcn_mfma_f32_16x16x32_f16(af[mt], bf[nt], acc[mt][nt], 0, 0, 0);
  }
  // C store (C/D: col = lane&15, row = (lane>>4)*4 + reg)
  int row0 = bm + wm + (lane >> 4) * 4;
  int col0 = bn + wn + (lane & 15);
#pragma unroll
  for (int mt = 0; mt < 2; ++mt)
#pragma unroll
    for (int nt = 0; nt < 4; ++nt) {
      _Float16* cp = C + (size_t)(row0 + mt * 16) * FDIM + col0 + nt * 16;
#pragma unroll
      for (int i = 0; i < 4; ++i) cp[(size_t)i * FDIM] = (_Float16)acc[mt][nt][i];
    }
  // attn-coef epilogue: wave covers exactly one head (64 cols); full dot per row.
  int head = (bn + wn) >> 6;
  float ps[2][4] = {}, pd[2][4] = {};
#pragma unroll
  for (int nt = 0; nt < 4; ++nt) {
    int c = bn + wn + (lane & 15) + nt * 16;
    float asv = a_s[c], adv = a_d[c];
#pragma unroll
    for (int mt = 0; mt < 2; ++mt)
#pragma unroll
      for (int i = 0; i < 4; ++i) {
        ps[mt][i] = fmaf(acc[mt][nt][i], asv, ps[mt][i]);
        pd[mt][i] = fmaf(acc[mt][nt][i], adv, pd[mt][i]);
      }
  }
#pragma unroll
  for (int off = 8; off >= 1; off >>= 1)
#pragma unroll
    for (int mt = 0; mt < 2; ++mt)
#pragma unroll
      for (int i = 0; i < 4; ++i) {
        ps[mt][i] += __shfl_xor(ps[mt][i], off);
        pd[mt][i] += __shfl_xor(pd[mt][i], off);
      }
  if ((lane & 15) == 0) {
#pragma unroll
    for (int mt = 0; mt < 2; ++mt)
#pragma unroll
      for (int i = 0; i < 4; ++i) {
        int r = row0 + mt * 16 + i;
        asn[r * 4 + head] = ps[mt][i];
        adn[r * 4 + head] = pd[mt][i];
      }
  }
}

// ---------------- cooperative mega-kernel: scan -> csr -> agg -> stats -> score ->
//                  topk -> pool(+remap L1) -> (final L2).  ALL phases grid-stride.
struct MegaArgs {
  const _Float16* h16; _Float16* o16;
  const int* srcE; const int* dstE;
  const float* asn; const float* adn;
  const int* deg; int* scanv; int* chunks; int* rowst; int* cursor;
  int* csrc; float* pexp;
  const float* bias;
  float* bnsum; float* bnsq; const float* g; const float* be; const float* w;
  float* score; float* vals; int* gidx; int* inv;
  _Float16* ah; float* pmax; float* psum;
  const int* src0; const int* dst0; int* ns; int* nd; int* deg2;
  const float* pmax1; const float* psum1; const float* Wl; const float* bl; float* outp;
};

template <int LAYER>
__global__ __launch_bounds__(256, 4) void mega_k(MegaArgs a) {
  constexpr int N = (LAYER == 1) ? NN1 : NN2;
  constexpr int CH = N / 1024;
  constexpr int NPG = (LAYER == 1) ? 1024 : 512;
  constexpr int KEEP = NPG / 2;
  constexpr int TPG = (LAYER == 1) ? 4 : 2;      // topk units per graph
  constexpr float INV_N = 1.0f / N;
  __shared__ float sv[1024];
  __shared__ int swsum[8];
  cg::grid_group grid = cg::this_grid();
  const int G = gridDim.x, blk = blockIdx.x, tid = threadIdx.x;
  const int lane = tid & 63;

  // ---- P0: per-chunk exclusive scan of deg+1 (self loop)
  for (int u = blk; u < CH; u += G) {
    int base = u * 1024 + tid * 4;
    int4 dv = *(const int4*)&a.deg[base];
    int v0 = dv.x + 1, v1 = dv.y + 1, v2 = dv.z + 1, v3 = dv.w + 1;
    int local = v0 + v1 + v2 + v3;
    int wv = tid >> 6;
    int x = local;
#pragma unroll
    for (int off = 1; off < 64; off <<= 1) {
      int t = __shfl_up(x, off);
      if (lane >= off) x += t;
    }
    if (lane == 63) swsum[wv] = x;
    __syncthreads();
    int woff = 0;
    for (int i = 0; i < wv; ++i) woff += swsum[i];
    int ex = woff + x - local;
    int4 o;
    o.x = ex; o.y = ex + v0; o.z = ex + v0 + v1; o.w = ex + v0 + v1 + v2;
    *(int4*)&a.scanv[base] = o;
    if (tid == 0) a.chunks[u] = swsum[0] + swsum[1] + swsum[2] + swsum[3];
    __syncthreads();
  }
  grid.sync();
  // ---- P1: add chunk prefix -> rowst + cursor
  for (int u = blk; u < CH; u += G) {
    int goff = 0;
    for (int i = 0; i < u; ++i) goff += a.chunks[i];
    int base = u * 1024 + tid * 4;
    int4 s4 = *(const int4*)&a.scanv[base];
    s4.x += goff; s4.y += goff; s4.z += goff; s4.w += goff;
    *(int4*)&a.rowst[base] = s4;
    *(int4*)&a.cursor[base] = s4;
    if (u == CH - 1 && tid == 0) a.rowst[N] = goff + a.chunks[u];
  }
  grid.sync();
  // ---- P2: csr fill (edges + self loops) + per-edge exp(lrelu(.))
  for (int e = blk * 256 + tid; e < NE + N; e += G * 256) {
    int s, d;
    if (e < NE) {
      d = a.dstE[e];
      if (d < 0) continue;
      s = a.srcE[e];
    } else {
      s = d = e - NE;
    }
    int pos = atomicAdd(&a.cursor[d], 1);
    a.csrc[pos] = s;
    float4 A4 = ((const float4*)a.asn)[s], B4 = ((const float4*)a.adn)[d];
    float4 p;
    p.x = expf(lrelu(A4.x + B4.x));
    p.y = expf(lrelu(A4.y + B4.y));
    p.z = expf(lrelu(A4.z + B4.z));
    p.w = expf(lrelu(A4.w + B4.w));
    ((float4*)a.pexp)[pos] = p;
  }
  grid.sync();
  // ---- P3: gat aggregate + GELU -> o16
  {
    int hw = lane >> 5, l = lane & 31;
    int c0 = l * 8, head = l >> 3;
    for (int d = blk * 4 + (tid >> 6); d < N; d += G * 4) {
      int beg = a.rowst[d], end = a.rowst[d + 1];
      float acc[8] = {};
      float de = 0.f;
      for (int i = beg; i < end; i += 2) {
        int e0 = i + hw;
        bool valid = e0 < end;
        int s = valid ? a.csrc[e0] : a.csrc[beg];
        float pw = valid ? a.pexp[e0 * 4 + head] : 0.f;
        float4 hv4 = *(const float4*)(a.h16 + (size_t)s * FDIM + c0);
        const _Float16* hh = (const _Float16*)&hv4;
        de += pw;
#pragma unroll
        for (int j = 0; j < 8; ++j) acc[j] = fmaf(pw, (float)hh[j], acc[j]);
      }
#pragma unroll
      for (int j = 0; j < 8; ++j) acc[j] += __shfl_xor(acc[j], 32);
      de += __shfl_xor(de, 32);
      if (hw == 0) {
        float inv = 1.f / de;
        _Float16 o[8];
#pragma unroll
        for (int j = 0; j < 8; ++j) o[j] = (_Float16)gelu(acc[j] * inv + a.bias[c0 + j]);
        *(float4*)(a.o16 + (size_t)d * FDIM + c0) = *(const float4*)o;
      }
    }
  }
  grid.sync();
  // ---- P4: BN stats
  for (int u = blk; u < 256; u += G) {
    constexpr int RPB = N / 256;
    int f = tid;
    float s = 0.f, sq = 0.f;
    for (int r = u * RPB; r < u * RPB + RPB; ++r) {
      float gg = (float)a.o16[(size_t)r * FDIM + f];
      s += gg;
      sq += gg * gg;
    }
    atomicAdd(&a.bnsum[f], s);
    atomicAdd(&a.bnsq[f], sq);
  }
  grid.sync();
  // ---- P5: score from raw o16 (BN deferred, affine fold)
  for (int q = blk; q < N / 4; q += G) {
    int node = q * 4 + (tid >> 6);
    int c0 = lane * 4;
    float2 raw = *(const float2*)(a.o16 + (size_t)node * FDIM + c0);
    const _Float16* hh = (const _Float16*)&raw;
    float p = 0.f, shw = 0.f, nw = 0.f;
#pragma unroll
    for (int j = 0; j < 4; ++j) {
      int c = c0 + j;
      float mean = a.bnsum[c] * INV_N;
      float var = a.bnsq[c] * INV_N - mean * mean;
      float sc = a.g[c] / sqrtf(var + BN_EPS);
      float sh = a.be[c] - mean * sc;
      float wv = a.w[c];
      p = fmaf((float)hh[j], sc * wv, p);
      shw = fmaf(sh, wv, shw);
      nw = fmaf(wv, wv, nw);
    }
#pragma unroll
    for (int off = 32; off > 0; off >>= 1) {
      p += __shfl_xor(p, off);
      shw += __shfl_xor(shw, off);
      nw += __shfl_xor(nw, off);
    }
    if (lane == 0) a.score[node] = (p + shw) / sqrtf(nw);
  }
  grid.sync();
  // ---- P6: topk by rank selection (TPG units/graph, 1 candidate/thread)
  for (int u = blk; u < NB * TPG; u += G) {
    int b = u / TPG;
    int cand = (u % TPG) * 256 + tid;
    for (int i = tid; i < NPG; i += 256) sv[i] = a.score[b * NPG + i];
    __syncthreads();
    float v = sv[cand];
    int rank = 0;
    const float4* sv4 = (const float4*)sv;
    for (int j4 = 0; j4 < NPG / 4; ++j4) {
      float4 qd = sv4[j4];
      int jb = j4 * 4;
      rank += (qd.x > v) || (qd.x == v && (jb + 0) < cand);
      rank += (qd.y > v) || (qd.y == v && (jb + 1) < cand);
      rank += (qd.z > v) || (qd.z == v && (jb + 2) < cand);
      rank += (qd.w > v) || (qd.w == v && (jb + 3) < cand);
    }
    if (rank < KEEP) {
      int r = b * KEEP + rank;
      a.vals[r] = v;
      int gg = b * NPG + cand;
      a.gidx[r] = gg;
      if (LAYER == 1) a.inv[gg] = r;
    }
    __syncthreads();
  }
  grid.sync();
  // ---- P7: pool gather (BN+tanh fused) + readout partials (+ remap/deg2 for L1)
  {
    constexpr int PU = (LAYER == 1) ? (NN2 / 16) : (NN3 / 16);
    constexpr int TOTU = (LAYER == 1) ? (PU + NE / 256) : PU;
    int f = tid;
    for (int u = blk; u < TOTU; u += G) {
      if (u < PU) {
        float mean = a.bnsum[f] * INV_N;
        float var = a.bnsq[f] * INV_N - mean * mean;
        float sc = a.g[f] / sqrtf(var + BN_EPS);
        float sh = a.be[f] - mean * sc;
        float mx = -3.0e38f, sm = 0.f;
        int r0 = u * 16;
        for (int j = 0; j < 16; ++j) {
          int r = r0 + j;
          float t = tanhf(a.vals[r]);
          float rawv = (float)a.o16[(size_t)a.gidx[r] * FDIM + f];
          float vv = fmaf(rawv, sc, sh) * t;
          if (LAYER == 1) a.ah[(size_t)r * FDIM + f] = (_Float16)vv;
          mx = fmaxf(mx, vv);
          sm += vv;
        }
        a.pmax[(size_t)u * FDIM + f] = mx;
        a.psum[(size_t)u * FDIM + f] = sm;
      } else if (LAYER == 1) {
        int e = (u - PU) * 256 + f;
        int aa = a.inv[a.src0[e]], bb = a.inv[a.dst0[e]];
        bool ok = (aa >= 0) && (bb >= 0);
        a.ns[e] = ok ? aa : -1;
        a.nd[e] = ok ? bb : -1;
        if (ok) atomicAdd(&a.deg2[bb], 1);
      }
    }
  }
  if (LAYER == 2) {
    grid.sync();
    // ---- P8: readout final (both layers) + output linear
    for (int u = blk; u < NB; u += G) {
      float* xs = sv;
      int b = u, f = tid;
      float mx1 = -3.0e38f, s1 = 0.f, mx2 = -3.0e38f, s2 = 0.f;
      for (int s = 0; s < KK1 / 16; ++s) {
        mx1 = fmaxf(mx1, a.pmax1[(size_t)(b * (KK1 / 16) + s) * FDIM + f]);
        s1 += a.psum1[(size_t)(b * (KK1 / 16) + s) * FDIM + f];
      }
      for (int s = 0; s < KK2 / 16; ++s) {
        mx2 = fmaxf(mx2, a.pmax[(size_t)(b * (KK2 / 16) + s) * FDIM + f]);
        s2 += a.psum[(size_t)(b * (KK2 / 16) + s) * FDIM + f];
      }
      xs[f] = mx1 + mx2;
      xs[FDIM + f] = s1 * (1.0f / KK1) + s2 * (1.0f / KK2);
      __syncthreads();
      float accv = a.bl[f];
      const float* wp = a.Wl + (size_t)f * 512;
      for (int j = 0; j < 512; ++j) accv = fmaf(xs[j], wp[j], accv);
      a.outp[b * OUT_DIM + f] = accv;
      __syncthreads();
    }
  }
}

static void launch_coop(const void* f, int want, void** params, hipStream_t stream) {
  // size grid to what the runtime will actually validate as co-resident
  int dev = 0;
  hipGetDevice(&dev);
  hipDeviceProp_t prop{};
  hipGetDeviceProperties(&prop, dev);
  int nCU = prop.multiProcessorCount > 0 ? prop.multiProcessorCount : 256;
  int occ = 0;
  hipOccupancyMaxActiveBlocksPerMultiprocessor(&occ, f, 256, 0);
  int g = (occ > 0) ? occ * nCU : 256;
  if (g > want) g = want;
  hipError_t e = hipLaunchCooperativeKernel(f, dim3(g), dim3(256), params, 0, stream);
  while (e != hipSuccess && g > 64) {   // defensive ladder; all phases are grid-stride
    g >>= 1;
    e = hipLaunchCooperativeKernel(f, dim3(g), dim3(256), params, 0, stream);
  }
}

extern "C" void kernel_launch(void* const* d_in, const int* in_sizes, int n_in,
                              void* d_out, int out_size, void* d_ws, size_t ws_size,
                              hipStream_t stream) {
  (void)in_sizes; (void)n_in; (void)out_size; (void)ws_size;
  const float* x   = (const float*)d_in[0];
  const int* eidx  = (const int*)d_in[1];
  const int* src   = eidx;
  const int* dst   = eidx + NE;
  const float* W1  = (const float*)d_in[3];
  const float* as1 = (const float*)d_in[4];
  const float* ad1 = (const float*)d_in[5];
  const float* b1  = (const float*)d_in[6];
  const float* g1  = (const float*)d_in[7];
  const float* be1 = (const float*)d_in[8];
  const float* pw1 = (const float*)d_in[9];
  const float* W2  = (const float*)d_in[10];
  const float* as2 = (const float*)d_in[11];
  const float* ad2 = (const float*)d_in[12];
  const float* b2  = (const float*)d_in[13];
  const float* g2  = (const float*)d_in[14];
  const float* be2 = (const float*)d_in[15];
  const float* pw2 = (const float*)d_in[16];
  const float* Wl  = (const float*)d_in[17];
  const float* bl  = (const float*)d_in[18];
  float* out = (float*)d_out;

  char* wsp = (char*)d_ws;
  size_t off = 0;
  auto alloc = [&](size_t bytes) -> void* {
    void* p = wsp + off;
    off += (bytes + 255) & ~(size_t)255;
    return p;
  };
  _Float16* h16 = (_Float16*)alloc((size_t)NN1 * FDIM * 2);
  _Float16* o16 = (_Float16*)alloc((size_t)NN1 * FDIM * 2);
  _Float16* ah  = (_Float16*)alloc((size_t)NN1 * IN_DIM * 2);
  _Float16* bt1 = (_Float16*)alloc((size_t)FDIM * IN_DIM * 2);
  _Float16* bt2 = (_Float16*)alloc((size_t)FDIM * FDIM * 2);
  float* asn    = (float*)alloc((size_t)NN1 * NHEADS * 4);
  float* adn    = (float*)alloc((size_t)NN1 * NHEADS * 4);
  float* pexp   = (float*)alloc((size_t)(NE + NN1) * 16);
  int*   deg1   = (int*)alloc((size_t)NN1 * 4);
  int*   deg2   = (int*)alloc((size_t)NN2 * 4);
  int*   rowst  = (int*)alloc((size_t)(NN1 + 1) * 4);
  int*   cursor = (int*)alloc((size_t)NN1 * 4);
  int*   scanv  = (int*)alloc((size_t)NN1 * 4);
  int*   chunks = (int*)alloc(64 * 4);
  int*   csrc   = (int*)alloc((size_t)(NE + NN1) * 4);
  int*   ns     = (int*)alloc((size_t)NE * 4);
  int*   nd     = (int*)alloc((size_t)NE * 4);
  int*   inv1   = (int*)alloc((size_t)NN1 * 4);
  float* score  = (float*)alloc((size_t)NN1 * 4);
  float* vals   = (float*)alloc((size_t)NN2 * 4);
  int*   gidx   = (int*)alloc((size_t)NN2 * 4);
  float* bnst   = (float*)alloc(1024 * 4);
  float* pmax1  = (float*)alloc((size_t)(NN2 / 16) * FDIM * 4);
  float* psum1  = (float*)alloc((size_t)(NN2 / 16) * FDIM * 4);
  float* pmax2  = (float*)alloc((size_t)(NN3 / 16) * FDIM * 4);
  float* psum2  = (float*)alloc((size_t)(NN3 / 16) * FDIM * 4);

  // 1) init
  init_k<<<4608, 256, 0, stream>>>((const float4*)x, (half4v*)ah, W1, bt1, W2, bt2,
                                   deg1, deg2, inv1, bnst);
  // 2) gemm1 + attn epilogue + deg1-count ride-along (1024 extra blocks)
  gemm_attn_k<IN_DIM, 512, true><<<dim3(2, 1024), 256, 0, stream>>>(
      ah, bt1, h16, as1, ad1, asn, adn, dst, deg1);
  // 3) MEGA1 (cooperative, self-sized grid)
  MegaArgs m1;
  m1.h16 = h16; m1.o16 = o16; m1.srcE = src; m1.dstE = dst;
  m1.asn = asn; m1.adn = adn;
  m1.deg = deg1; m1.scanv = scanv; m1.chunks = chunks; m1.rowst = rowst; m1.cursor = cursor;
  m1.csrc = csrc; m1.pexp = pexp; m1.bias = b1;
  m1.bnsum = bnst; m1.bnsq = bnst + 256; m1.g = g1; m1.be = be1; m1.w = pw1;
  m1.score = score; m1.vals = vals; m1.gidx = gidx; m1.inv = inv1;
  m1.ah = ah; m1.pmax = pmax1; m1.psum = psum1;
  m1.src0 = src; m1.dst0 = dst; m1.ns = ns; m1.nd = nd; m1.deg2 = deg2;
  m1.pmax1 = nullptr; m1.psum1 = nullptr; m1.Wl = nullptr; m1.bl = nullptr; m1.outp = nullptr;
  {
    void* p1[] = {(void*)&m1};
    const void* f1 = (const void*)static_cast<void (*)(MegaArgs)>(mega_k<1>);
    launch_coop(f1, 1024, p1, stream);
  }
  // 4) gemm2 + attn epilogue
  gemm_attn_k<FDIM, 256, false><<<dim3(2, 256), 256, 0, stream>>>(
      ah, bt2, h16, as2, ad2, asn, adn, nullptr, nullptr);
  // 5) MEGA2 (cooperative, includes final)
  MegaArgs m2 = m1;
  m2.srcE = ns; m2.dstE = nd; m2.deg = deg2; m2.bias = b2;
  m2.bnsum = bnst + 512; m2.bnsq = bnst + 768; m2.g = g2; m2.be = be2; m2.w = pw2;
  m2.inv = nullptr; m2.ah = nullptr; m2.pmax = pmax2; m2.psum = psum2;
  m2.pmax1 = pmax1; m2.psum1 = psum1; m2.Wl = Wl; m2.bl = bl; m2.outp = out;
  {
    void* p2[] = {(void*)&m2};
    const void* f2 = (const void*)static_cast<void (*)(MegaArgs)>(mega_k<2>);
    launch_coop(f2, 1024, p2, stream);
  }
}

// Round 9
// 355.031 us; speedup vs baseline: 4.5253x; 4.5253x over previous
//
#include <hip/hip_runtime.h>

#define NN1 32768
#define NE  262144
#define FDIM 256
#define NHEADS 4
#define IN_DIM 128
#define NB 32
#define KK1 512
#define NN2 16384   // NB*KK1
#define KK2 256
#define NN3 8192    // NB*KK2
#define OUT_DIM 256
#define BN_EPS 1e-5f
#define NEG_SLOPE 0.2f

typedef _Float16 half8 __attribute__((ext_vector_type(8)));
typedef _Float16 half4v __attribute__((ext_vector_type(4)));
typedef float floatx4 __attribute__((ext_vector_type(4)));

__device__ __forceinline__ float lrelu(float x) { return x >= 0.f ? x : NEG_SLOPE * x; }
__device__ __forceinline__ float gelu(float v) {
  return 0.5f * v * (1.0f + erff(v * 0.7071067811865476f));
}
// XCD swizzle: total blocks = 32*U (U units/graph). blk%8 -> XCD; XCD x owns graphs {x,x+8,x+16,x+24}.
#define SWIZ(U) int g, u; { int _x = blockIdx.x & 7, _i = blockIdx.x >> 3; g = _x + 8 * (_i / (U)); u = _i % (U); }

// ---------- init: x->fp16, W1^T, W2^T, zero deg1/deg2/inv1/bnstats ----------
__global__ void init_k(const float4* __restrict__ x, half4v* __restrict__ ah,
                       const float* __restrict__ W1, _Float16* __restrict__ bt1,
                       const float* __restrict__ W2, _Float16* __restrict__ bt2,
                       int* __restrict__ deg1, int* __restrict__ deg2,
                       int* __restrict__ inv1, float* __restrict__ bnst) {
  int blk = blockIdx.x, tid = threadIdx.x;
  if (blk < 4096) {
    int i = blk * 256 + tid;
    float4 v = x[i];
    half4v h;
    h[0] = (_Float16)v.x; h[1] = (_Float16)v.y; h[2] = (_Float16)v.z; h[3] = (_Float16)v.w;
    ah[i] = h;
  } else if (blk < 4224) {                // W1[128][256] -> bt1[256][128]
    int idx = (blk - 4096) * 256 + tid;
    int n = idx >> 7, k = idx & 127;
    bt1[idx] = (_Float16)W1[k * FDIM + n];
  } else if (blk < 4480) {                // W2[256][256] -> bt2[256][256]
    int idx = (blk - 4224) * 256 + tid;
    int n = idx >> 8, k = idx & 255;
    bt2[idx] = (_Float16)W2[k * FDIM + n];
  } else {
    int i = (blk - 4480) * 256 + tid;
    deg1[i] = 0;
    inv1[i] = -1;
    if (i < NN2) deg2[i] = 0;
    if (i < 1024) bnst[i] = 0.f;
  }
}

// ---------------- MFMA fp16 GEMM + fused attn-coef epilogue (+ optional deg ride-along)
template <int K, int MBLK, bool RIDE>
__global__ void gemm_attn_k(const _Float16* __restrict__ A, const _Float16* __restrict__ BT,
                            _Float16* __restrict__ C, const float* __restrict__ a_s,
                            const float* __restrict__ a_d, float* __restrict__ asn,
                            float* __restrict__ adn, const int* __restrict__ dstE,
                            int* __restrict__ deg) {
  if (RIDE && (int)blockIdx.y >= MBLK) {
    int unit = blockIdx.x + 2 * (blockIdx.y - MBLK);
    int e = unit * 256 + threadIdx.x;
    if (e < NE) {
      int dd = dstE[e];
      if (dd >= 0) atomicAdd(&deg[dd], 1);
    }
    return;
  }
  __shared__ _Float16 As[64 * 40];
  __shared__ _Float16 Bs[128 * 40];
  int tid = threadIdx.x;
  int lane = tid & 63, w = tid >> 6;
  int bm = blockIdx.y * 64, bn = blockIdx.x * 128;
  int wm = (w & 1) * 32, wn = (w >> 1) * 64;
  floatx4 acc[2][4] = {};
  int ar = tid >> 2, ac = (tid & 3) * 8;
  int br = tid >> 1, bc = (tid & 1) * 16;
  int fm = lane & 15, fq = (lane >> 4) * 8;
  for (int k0 = 0; k0 < K; k0 += 32) {
    __syncthreads();
    *(half8*)&As[ar * 40 + ac] = *(const half8*)&A[(size_t)(bm + ar) * K + k0 + ac];
    *(half8*)&Bs[br * 40 + bc] = *(const half8*)&BT[(size_t)(bn + br) * K + k0 + bc];
    *(half8*)&Bs[br * 40 + bc + 8] = *(const half8*)&BT[(size_t)(bn + br) * K + k0 + bc + 8];
    __syncthreads();
    half8 af[2], bf[4];
#pragma unroll
    for (int mt = 0; mt < 2; ++mt)
      af[mt] = *(const half8*)&As[(wm + mt * 16 + fm) * 40 + fq];
#pragma unroll
    for (int nt = 0; nt < 4; ++nt)
      bf[nt] = *(const half8*)&Bs[(wn + nt * 16 + fm) * 40 + fq];
#pragma unroll
    for (int mt = 0; mt < 2; ++mt)
#pragma unroll
      for (int nt = 0; nt < 4; ++nt)
        acc[mt][nt] = __builtin_amdgcn_mfma_f32_16x16x32_f16(af[mt], bf[nt], acc[mt][nt], 0, 0, 0);
  }
  int row0 = bm + wm + (lane >> 4) * 4;
  int col0 = bn + wn + (lane & 15);
#pragma unroll
  for (int mt = 0; mt < 2; ++mt)
#pragma unroll
    for (int nt = 0; nt < 4; ++nt) {
      _Float16* cp = C + (size_t)(row0 + mt * 16) * FDIM + col0 + nt * 16;
#pragma unroll
      for (int i = 0; i < 4; ++i) cp[(size_t)i * FDIM] = (_Float16)acc[mt][nt][i];
    }
  // attn-coef epilogue (wave = one head)
  int head = (bn + wn) >> 6;
  float ps[2][4] = {}, pd[2][4] = {};
#pragma unroll
  for (int nt = 0; nt < 4; ++nt) {
    int c = bn + wn + (lane & 15) + nt * 16;
    float asv = a_s[c], adv = a_d[c];
#pragma unroll
    for (int mt = 0; mt < 2; ++mt)
#pragma unroll
      for (int i = 0; i < 4; ++i) {
        ps[mt][i] = fmaf(acc[mt][nt][i], asv, ps[mt][i]);
        pd[mt][i] = fmaf(acc[mt][nt][i], adv, pd[mt][i]);
      }
  }
#pragma unroll
  for (int off = 8; off >= 1; off >>= 1)
#pragma unroll
    for (int mt = 0; mt < 2; ++mt)
#pragma unroll
      for (int i = 0; i < 4; ++i) {
        ps[mt][i] += __shfl_xor(ps[mt][i], off);
        pd[mt][i] += __shfl_xor(pd[mt][i], off);
      }
  if ((lane & 15) == 0) {
#pragma unroll
    for (int mt = 0; mt < 2; ++mt)
#pragma unroll
      for (int i = 0; i < 4; ++i) {
        int r = row0 + mt * 16 + i;
        asn[r * 4 + head] = ps[mt][i];
        adn[r * 4 + head] = pd[mt][i];
      }
  }
}

// ---------------- fused 2-level scan of (deg+1): block b redundantly sums deg[0..b*1024)
template <int N>
__global__ void scanF_k(const int* __restrict__ deg, int* __restrict__ rowst,
                        int* __restrict__ cursor) {
  __shared__ int red[4];
  __shared__ int swsum[4];
  int b = blockIdx.x, tid = threadIdx.x, lane = tid & 63, wv = tid >> 6;
  int part = 0;
  for (int idx = tid * 4; idx < b * 1024; idx += 1024) {
    int4 v = *(const int4*)&deg[idx];
    part += v.x + v.y + v.z + v.w;
  }
#pragma unroll
  for (int off = 32; off > 0; off >>= 1) part += __shfl_xor(part, off);
  if (lane == 0) red[wv] = part;
  __syncthreads();
  int goff = red[0] + red[1] + red[2] + red[3] + b * 1024;  // + self loops of prior chunks
  int base = b * 1024 + tid * 4;
  int4 dv = *(const int4*)&deg[base];
  int v0 = dv.x + 1, v1 = dv.y + 1, v2 = dv.z + 1, v3 = dv.w + 1;
  int local = v0 + v1 + v2 + v3;
  int xx = local;
#pragma unroll
  for (int off = 1; off < 64; off <<= 1) {
    int t = __shfl_up(xx, off);
    if (lane >= off) xx += t;
  }
  if (lane == 63) swsum[wv] = xx;
  __syncthreads();
  int woff = 0;
  for (int i = 0; i < wv; ++i) woff += swsum[i];
  int ex = goff + woff + xx - local;
  int4 o;
  o.x = ex; o.y = ex + v0; o.z = ex + v0 + v1; o.w = ex + v0 + v1 + v2;
  *(int4*)&rowst[base] = o;
  *(int4*)&cursor[base] = o;
  if (b == (N / 1024) - 1 && tid == 0)
    rowst[N] = goff + swsum[0] + swsum[1] + swsum[2] + swsum[3];
}

// ---------------- CSR fill (XCD-swizzled): EU edge-units + SU selfloop-units per graph
template <int NPG, int EU, int SU>
__global__ void csr_fill_k(const int* __restrict__ src, const int* __restrict__ dst,
                           int* __restrict__ cursor, const float4* __restrict__ asn4,
                           const float4* __restrict__ adn4, int* __restrict__ csrc,
                           float4* __restrict__ pexp) {
  int tid = threadIdx.x;
  int s, d;
  if ((int)blockIdx.x < 32 * EU) {
    SWIZ(EU);
    int e = g * 8192 + u * 256 + tid;
    d = dst[e];
    if (d < 0) return;
    s = src[e];
  } else {
    int bb = blockIdx.x - 32 * EU;
    int _x = bb & 7, _i = bb >> 3;
    int g = _x + 8 * (_i / SU), u = _i % SU;
    s = d = g * NPG + u * 256 + tid;
  }
  int pos = atomicAdd(&cursor[d], 1);
  csrc[pos] = s;
  float4 A4 = asn4[s], B4 = adn4[d];
  float4 p;
  p.x = expf(lrelu(A4.x + B4.x));
  p.y = expf(lrelu(A4.y + B4.y));
  p.z = expf(lrelu(A4.z + B4.z));
  p.w = expf(lrelu(A4.w + B4.w));
  pexp[pos] = p;
}

// ---------------- GAT aggregate + GELU -> o16 (XCD-swizzled, U = NPG/4 units/graph)
template <int NPG>
__global__ void gat_agg_k(const _Float16* __restrict__ h, const int* __restrict__ rowstart,
                          const int* __restrict__ csrc, const float* __restrict__ pexpf,
                          const float* __restrict__ bias, _Float16* __restrict__ out) {
  SWIZ(NPG / 4);
  int tid = threadIdx.x, lane = tid & 63;
  int hw = lane >> 5, l = lane & 31;
  int d = g * NPG + u * 4 + (tid >> 6);
  int beg = rowstart[d], end = rowstart[d + 1];
  int c0 = l * 8, head = l >> 3;
  float acc[8] = {};
  float de = 0.f;
  for (int i = beg; i < end; i += 2) {
    int e0 = i + hw;
    bool valid = e0 < end;
    int s = valid ? csrc[e0] : csrc[beg];
    float pw = valid ? pexpf[e0 * 4 + head] : 0.f;
    float4 hv4 = *(const float4*)(h + (size_t)s * FDIM + c0);
    const _Float16* hh = (const _Float16*)&hv4;
    de += pw;
#pragma unroll
    for (int j = 0; j < 8; ++j) acc[j] = fmaf(pw, (float)hh[j], acc[j]);
  }
#pragma unroll
  for (int j = 0; j < 8; ++j) acc[j] += __shfl_xor(acc[j], 32);
  de += __shfl_xor(de, 32);
  if (hw == 0) {
    float inv = 1.f / de;
    _Float16 o[8];
#pragma unroll
    for (int j = 0; j < 8; ++j) o[j] = (_Float16)gelu(acc[j] * inv + bias[c0 + j]);
    *(float4*)(out + (size_t)d * FDIM + c0) = *(const float4*)o;
  }
}

// ---------------- BN stats (XCD-swizzled, 8 units/graph)
template <int NPG>
__global__ void stats_k(const _Float16* __restrict__ x, float* __restrict__ sum,
                        float* __restrict__ sumsq) {
  SWIZ(8);
  constexpr int RPB = NPG / 8;
  int f = threadIdx.x;
  int r0 = g * NPG + u * RPB;
  float s = 0.f, sq = 0.f;
  for (int r = r0; r < r0 + RPB; ++r) {
    float gg = (float)x[(size_t)r * FDIM + f];
    s += gg;
    sq += gg * gg;
  }
  atomicAdd(&sum[f], s);
  atomicAdd(&sumsq[f], sq);
}

// ---------------- score (deferred BN affine fold; XCD-swizzled, NPG/4 units/graph)
template <int NPG, int NTOT>
__global__ void score_k(const _Float16* __restrict__ x, const float* __restrict__ bnsum,
                        const float* __restrict__ bnsq, const float* __restrict__ g_,
                        const float* __restrict__ be, const float* __restrict__ w,
                        float* __restrict__ score) {
  SWIZ(NPG / 4);
  constexpr float INV_N = 1.0f / NTOT;
  int tid = threadIdx.x, lane = tid & 63;
  int node = g * NPG + u * 4 + (tid >> 6);
  int c0 = lane * 4;
  float2 raw = *(const float2*)(x + (size_t)node * FDIM + c0);
  const _Float16* hh = (const _Float16*)&raw;
  float p = 0.f, shw = 0.f, nw = 0.f;
#pragma unroll
  for (int j = 0; j < 4; ++j) {
    int c = c0 + j;
    float mean = bnsum[c] * INV_N;
    float var = bnsq[c] * INV_N - mean * mean;
    float sc = g_[c] / sqrtf(var + BN_EPS);
    float sh = be[c] - mean * sc;
    float wv = w[c];
    p = fmaf((float)hh[j], sc * wv, p);
    shw = fmaf(sh, wv, shw);
    nw = fmaf(wv, wv, nw);
  }
#pragma unroll
  for (int off = 32; off > 0; off >>= 1) {
    p += __shfl_xor(p, off);
    shw += __shfl_xor(shw, off);
    nw += __shfl_xor(nw, off);
  }
  if (lane == 0) score[node] = (p + shw) / sqrtf(nw);
}

// ---------------- topk by rank selection (XCD-swizzled, TPG units/graph)
template <int NPG, int KEEP>
__global__ void topk_k(const float* __restrict__ score, float* __restrict__ vals,
                       int* __restrict__ gidx, int* __restrict__ inv) {
  constexpr int TPG = NPG / 256;
  SWIZ(TPG);
  __shared__ __align__(16) float sv[NPG];
  int tid = threadIdx.x;
  for (int i = tid; i < NPG; i += 256) sv[i] = score[g * NPG + i];
  __syncthreads();
  int cand = u * 256 + tid;
  float v = sv[cand];
  int rank = 0;
  const float4* sv4 = (const float4*)sv;
  for (int j4 = 0; j4 < NPG / 4; ++j4) {
    float4 qd = sv4[j4];
    int jb = j4 * 4;
    rank += (qd.x > v) || (qd.x == v && (jb + 0) < cand);
    rank += (qd.y > v) || (qd.y == v && (jb + 1) < cand);
    rank += (qd.z > v) || (qd.z == v && (jb + 2) < cand);
    rank += (qd.w > v) || (qd.w == v && (jb + 3) < cand);
  }
  if (rank < KEEP) {
    int r = g * KEEP + rank;
    vals[r] = v;
    int gg2 = g * NPG + cand;
    gidx[r] = gg2;
    if (inv) inv[gg2] = r;
  }
}

// ---------------- pool (BN+tanh fused gather + readout partials), L1 adds remap+deg2 ride
template <int NPG, int KEEP, bool EMIT, bool REMAP, int NTOT>
__global__ void pool_k(const _Float16* __restrict__ x, const int* __restrict__ gidx,
                       const float* __restrict__ vals, const float* __restrict__ bnsum,
                       const float* __restrict__ bnsq, const float* __restrict__ g_,
                       const float* __restrict__ be, _Float16* __restrict__ ah,
                       float* __restrict__ pmax, float* __restrict__ psum,
                       const int* __restrict__ src0, const int* __restrict__ dst0,
                       const int* __restrict__ inv, int* __restrict__ ns,
                       int* __restrict__ nd, int* __restrict__ deg2) {
  constexpr int PU = KEEP / 16;            // pool units per graph
  constexpr float INV_N = 1.0f / NTOT;
  int f = threadIdx.x;
  if ((int)blockIdx.x < 32 * PU) {
    SWIZ(PU);
    float mean = bnsum[f] * INV_N;
    float var = bnsq[f] * INV_N - mean * mean;
    float sc = g_[f] / sqrtf(var + BN_EPS);
    float sh = be[f] - mean * sc;
    float mx = -3.0e38f, sm = 0.f;
    int r0 = g * KEEP + u * 16;
#pragma unroll 4
    for (int j = 0; j < 16; ++j) {
      int r = r0 + j;
      float t = tanhf(vals[r]);
      float rawv = (float)x[(size_t)gidx[r] * FDIM + f];
      float vv = fmaf(rawv, sc, sh) * t;
      if (EMIT) ah[(size_t)r * FDIM + f] = (_Float16)vv;
      mx = fmaxf(mx, vv);
      sm += vv;
    }
    int blk = g * PU + u;
    pmax[(size_t)blk * FDIM + f] = mx;
    psum[(size_t)blk * FDIM + f] = sm;
  } else if (REMAP) {
    int bb = blockIdx.x - 32 * PU;
    int _x = bb & 7, _i = bb >> 3;
    int g = _x + 8 * (_i / 32), u = _i % 32;
    int e = g * 8192 + u * 256 + f;
    int aa = inv[src0[e]], b2 = inv[dst0[e]];
    bool ok = (aa >= 0) && (b2 >= 0);
    ns[e] = ok ? aa : -1;
    nd[e] = ok ? b2 : -1;
    if (ok) atomicAdd(&deg2[b2], 1);
  }
}

// ---------------- readout-final (both layers) + output linear
__global__ void final_k(const float* __restrict__ pmax1, const float* __restrict__ psum1,
                        const float* __restrict__ pmax2, const float* __restrict__ psum2,
                        const float* __restrict__ Wl, const float* __restrict__ bl,
                        float* __restrict__ out) {
  __shared__ float xs[2 * FDIM];
  int b = blockIdx.x, f = threadIdx.x;
  float mx1 = -3.0e38f, s1 = 0.f, mx2 = -3.0e38f, s2 = 0.f;
  for (int s = 0; s < KK1 / 16; ++s) {
    mx1 = fmaxf(mx1, pmax1[(size_t)(b * (KK1 / 16) + s) * FDIM + f]);
    s1 += psum1[(size_t)(b * (KK1 / 16) + s) * FDIM + f];
  }
  for (int s = 0; s < KK2 / 16; ++s) {
    mx2 = fmaxf(mx2, pmax2[(size_t)(b * (KK2 / 16) + s) * FDIM + f]);
    s2 += psum2[(size_t)(b * (KK2 / 16) + s) * FDIM + f];
  }
  xs[f] = mx1 + mx2;
  xs[FDIM + f] = s1 * (1.0f / KK1) + s2 * (1.0f / KK2);
  __syncthreads();
  float acc = bl[f];
  const float* wp = Wl + (size_t)f * 512;
  for (int j = 0; j < 512; ++j) acc = fmaf(xs[j], wp[j], acc);
  out[b * OUT_DIM + f] = acc;
}

extern "C" void kernel_launch(void* const* d_in, const int* in_sizes, int n_in,
                              void* d_out, int out_size, void* d_ws, size_t ws_size,
                              hipStream_t stream) {
  (void)in_sizes; (void)n_in; (void)out_size; (void)ws_size;
  const float* x   = (const float*)d_in[0];
  const int* eidx  = (const int*)d_in[1];
  const int* src   = eidx;
  const int* dst   = eidx + NE;
  const float* W1  = (const float*)d_in[3];
  const float* as1 = (const float*)d_in[4];
  const float* ad1 = (const float*)d_in[5];
  const float* b1  = (const float*)d_in[6];
  const float* g1  = (const float*)d_in[7];
  const float* be1 = (const float*)d_in[8];
  const float* pw1 = (const float*)d_in[9];
  const float* W2  = (const float*)d_in[10];
  const float* as2 = (const float*)d_in[11];
  const float* ad2 = (const float*)d_in[12];
  const float* b2  = (const float*)d_in[13];
  const float* g2  = (const float*)d_in[14];
  const float* be2 = (const float*)d_in[15];
  const float* pw2 = (const float*)d_in[16];
  const float* Wl  = (const float*)d_in[17];
  const float* bl  = (const float*)d_in[18];
  float* out = (float*)d_out;

  char* wsp = (char*)d_ws;
  size_t off = 0;
  auto alloc = [&](size_t bytes) -> void* {
    void* p = wsp + off;
    off += (bytes + 255) & ~(size_t)255;
    return p;
  };
  _Float16* h16 = (_Float16*)alloc((size_t)NN1 * FDIM * 2);
  _Float16* o16 = (_Float16*)alloc((size_t)NN1 * FDIM * 2);
  _Float16* ah  = (_Float16*)alloc((size_t)NN1 * IN_DIM * 2);
  _Float16* bt1 = (_Float16*)alloc((size_t)FDIM * IN_DIM * 2);
  _Float16* bt2 = (_Float16*)alloc((size_t)FDIM * FDIM * 2);
  float* asn    = (float*)alloc((size_t)NN1 * NHEADS * 4);
  float* adn    = (float*)alloc((size_t)NN1 * NHEADS * 4);
  float* pexp   = (float*)alloc((size_t)(NE + NN1) * 16);
  int*   deg1   = (int*)alloc((size_t)NN1 * 4);
  int*   deg2   = (int*)alloc((size_t)NN2 * 4);
  int*   rowst  = (int*)alloc((size_t)(NN1 + 1) * 4);
  int*   cursor = (int*)alloc((size_t)NN1 * 4);
  int*   csrc   = (int*)alloc((size_t)(NE + NN1) * 4);
  int*   ns     = (int*)alloc((size_t)NE * 4);
  int*   nd     = (int*)alloc((size_t)NE * 4);
  int*   inv1   = (int*)alloc((size_t)NN1 * 4);
  float* score  = (float*)alloc((size_t)NN1 * 4);
  float* vals   = (float*)alloc((size_t)NN2 * 4);
  int*   gidx   = (int*)alloc((size_t)NN2 * 4);
  float* bnst   = (float*)alloc(1024 * 4);
  float* pmax1  = (float*)alloc((size_t)(NN2 / 16) * FDIM * 4);
  float* psum1  = (float*)alloc((size_t)(NN2 / 16) * FDIM * 4);
  float* pmax2  = (float*)alloc((size_t)(NN3 / 16) * FDIM * 4);
  float* psum2  = (float*)alloc((size_t)(NN3 / 16) * FDIM * 4);

  // ---------- layer 1 ----------
  init_k<<<4608, 256, 0, stream>>>((const float4*)x, (half4v*)ah, W1, bt1, W2, bt2,
                                   deg1, deg2, inv1, bnst);
  gemm_attn_k<IN_DIM, 512, true><<<dim3(2, 1024), 256, 0, stream>>>(
      ah, bt1, h16, as1, ad1, asn, adn, dst, deg1);
  scanF_k<NN1><<<NN1 / 1024, 256, 0, stream>>>(deg1, rowst, cursor);
  csr_fill_k<1024, 32, 4><<<1024 + 128, 256, 0, stream>>>(
      src, dst, cursor, (const float4*)asn, (const float4*)adn, csrc, (float4*)pexp);
  gat_agg_k<1024><<<NN1 / 4, 256, 0, stream>>>(h16, rowst, csrc, pexp, b1, o16);
  stats_k<1024><<<256, 256, 0, stream>>>(o16, bnst, bnst + 256);
  score_k<1024, NN1><<<NN1 / 4, 256, 0, stream>>>(o16, bnst, bnst + 256, g1, be1, pw1, score);
  topk_k<1024, 512><<<NB * 4, 256, 0, stream>>>(score, vals, gidx, inv1);
  pool_k<1024, 512, true, true, NN1><<<1024 + 1024, 256, 0, stream>>>(
      o16, gidx, vals, bnst, bnst + 256, g1, be1, ah, pmax1, psum1,
      src, dst, inv1, ns, nd, deg2);
  // ---------- layer 2 ----------
  gemm_attn_k<FDIM, 256, false><<<dim3(2, 256), 256, 0, stream>>>(
      ah, bt2, h16, as2, ad2, asn, adn, nullptr, nullptr);
  scanF_k<NN2><<<NN2 / 1024, 256, 0, stream>>>(deg2, rowst, cursor);
  csr_fill_k<512, 32, 2><<<1024 + 64, 256, 0, stream>>>(
      ns, nd, cursor, (const float4*)asn, (const float4*)adn, csrc, (float4*)pexp);
  gat_agg_k<512><<<NN2 / 4, 256, 0, stream>>>(h16, rowst, csrc, pexp, b2, o16);
  stats_k<512><<<256, 256, 0, stream>>>(o16, bnst + 512, bnst + 768);
  score_k<512, NN2><<<NN2 / 4, 256, 0, stream>>>(o16, bnst + 512, bnst + 768, g2, be2, pw2,
                                                 score);
  topk_k<512, 256><<<NB * 2, 256, 0, stream>>>(score, vals, gidx, nullptr);
  pool_k<512, 256, false, false, NN2><<<512, 256, 0, stream>>>(
      o16, gidx, vals, bnst + 512, bnst + 768, g2, be2, nullptr, pmax2, psum2,
      nullptr, nullptr, nullptr, nullptr, nullptr, nullptr);
  // ---------- final ----------
  final_k<<<NB, 256, 0, stream>>>(pmax1, psum1, pmax2, psum2, Wl, bl, out);
}